// Round 13
// baseline (233.053 us; speedup 1.0000x reference)
//
#include <hip/hip_runtime.h>
#include <hip/hip_bf16.h>

#define B_ 2
#define S_ 2048
#define D_ 1024
#define H_ 16
#define HD_ 64

typedef __attribute__((ext_vector_type(8))) short short8;
typedef __attribute__((ext_vector_type(4))) short short4v;
typedef __attribute__((ext_vector_type(4))) float float4v;

typedef const __attribute__((address_space(1))) void* gas_ptr;
typedef __attribute__((address_space(3))) void* las_ptr;

static __device__ inline void gl_lds16(const void* g, void* l) {
  __builtin_amdgcn_global_load_lds((gas_ptr)g, (las_ptr)l, 16, 0, 0);
}

static __device__ inline short f2bs(float x) {
  __hip_bfloat16 h = __float2bfloat16(x);
  union { __hip_bfloat16 h; short s; } u; u.h = h; return u.s;
}
static __device__ inline float bs2f(short s) {
  union { short s; __hip_bfloat16 h; } u; u.s = s; return __bfloat162float(u.h);
}
// packed f32x8 -> bf16x8 (v_cvt_pk_bf16_f32 x4); a = key-tile lo, b = key-tile hi
static __device__ inline short8 pk8(const float* a, const float* b) {
  union { __hip_bfloat162 h[4]; short8 s; } u;
  u.h[0] = __float22bfloat162_rn(float2{a[0], a[1]});
  u.h[1] = __float22bfloat162_rn(float2{a[2], a[3]});
  u.h[2] = __float22bfloat162_rn(float2{b[0], b[1]});
  u.h[3] = __float22bfloat162_rn(float2{b[2], b[3]});
  return u.s;
}

static __device__ inline float4v mfma32(short8 a, short8 b, float4v c) {
  return __builtin_amdgcn_mfma_f32_16x16x32_bf16(a, b, c, 0, 0, 0);
}

// ------- Stage A: prep (r26): 512 blocks; 4 hs-cvt jobs + 1 W-transpose job.
__global__ __launch_bounds__(256) void prep(
    const float* __restrict__ hs, __hip_bfloat16* __restrict__ hsb,
    const float* __restrict__ Wq, const float* __restrict__ Wk,
    __hip_bfloat16* __restrict__ Wqt, __hip_bfloat16* __restrict__ Wkt) {
  __shared__ float t[64][65];
  const int id = blockIdx.x;
#pragma unroll
  for (int j = 0; j < 4; ++j) {
    const size_t i = (((size_t)id * 4 + j) * 256 + threadIdx.x) * 8;
    const float4v a0 = ((const float4v*)(hs + i))[0];
    const float4v a1 = ((const float4v*)(hs + i))[1];
    short8 s;
#pragma unroll
    for (int jj = 0; jj < 4; ++jj) { s[jj] = f2bs(a0[jj]); s[4 + jj] = f2bs(a1[jj]); }
    *(short8*)(hsb + i) = s;
  }
  const float* W = (id >> 8) ? Wk : Wq;
  __hip_bfloat16* Wt = (id >> 8) ? Wkt : Wqt;
  const int n0 = (id & 15) * 64, k0 = ((id >> 4) & 15) * 64;
  const int c = threadIdx.x & 63, r0 = threadIdx.x >> 6;
  for (int i = 0; i < 16; ++i) {
    const int r = i * 4 + r0;
    t[c][r] = W[(size_t)(k0 + r) * D_ + n0 + c];
  }
  __syncthreads();
  for (int i = 0; i < 16; ++i) {
    const int rr = i * 4 + r0;
    Wt[(size_t)(n0 + rr) * D_ + k0 + c] = __float2bfloat16(t[rr][c]);
  }
}

// ---- Stage B (fused GEMM+prep): r26 — XCD owns one W-panel (xcd = nt). ----
__global__ __launch_bounds__(256, 2) void gemm_fused(
    const __hip_bfloat16* __restrict__ hsb,
    const __hip_bfloat16* __restrict__ Wqt, const __hip_bfloat16* __restrict__ Wkt,
    const float* __restrict__ bq, const float* __restrict__ bk,
    __hip_bfloat16* __restrict__ q_out, __hip_bfloat16* __restrict__ kt_out,
    __hip_bfloat16* __restrict__ vT) {
  const int id = blockIdx.x;
  const int nt = id & 7;                           // n-block 0..7 == XCD
  const int mt = id >> 3;                          // m-tile 0..63
  const int n0 = nt * 128, m0 = mt * 64;
  __shared__ __hip_bfloat16 As[2][64 * 32];    // 8KB
  __shared__ __hip_bfloat16 Bq[2][128 * 32];   // 16KB
  __shared__ __hip_bfloat16 Bk[2][128 * 32];   // 16KB
  const int tid = threadIdx.x, wid = tid >> 6, lane = tid & 63;
  const int wm = (wid >> 1) * 32, wn = (wid & 1) * 64;
  const int l15 = lane & 15, l4 = lane >> 4;
  const float4v zz = {0.f, 0.f, 0.f, 0.f};
  float4v accq[2][4], acck[2][4];
  for (int i = 0; i < 2; ++i)
    for (int j = 0; j < 4; ++j) { accq[i][j] = zz; acck[i][j] = zz; }
  const int lrow = wid * 16 + (lane >> 2);
  const int lk8 = (((lane & 3) ^ ((lane >> 3) & 3)) * 8);
  {
    gl_lds16(hsb + (size_t)(m0 + lrow) * D_ + lk8, As[0] + wid * 512);
    gl_lds16(Wqt + (size_t)(n0 + lrow) * D_ + lk8, Bq[0] + wid * 512);
    gl_lds16(Wqt + (size_t)(n0 + 64 + lrow) * D_ + lk8, Bq[0] + 2048 + wid * 512);
    gl_lds16(Wkt + (size_t)(n0 + lrow) * D_ + lk8, Bk[0] + wid * 512);
    gl_lds16(Wkt + (size_t)(n0 + 64 + lrow) * D_ + lk8, Bk[0] + 2048 + wid * 512);
  }
  int p = 0;
  for (int kb = 0; kb < 32; ++kb) {
    __syncthreads();  // buf[p] staged (vm drained); prev frag reads done
    if (kb < 31) {
      const int kc = (kb + 1) * 32 + lk8;
      gl_lds16(hsb + (size_t)(m0 + lrow) * D_ + kc, As[p ^ 1] + wid * 512);
      gl_lds16(Wqt + (size_t)(n0 + lrow) * D_ + kc, Bq[p ^ 1] + wid * 512);
      gl_lds16(Wqt + (size_t)(n0 + 64 + lrow) * D_ + kc, Bq[p ^ 1] + 2048 + wid * 512);
      gl_lds16(Wkt + (size_t)(n0 + lrow) * D_ + kc, Bk[p ^ 1] + wid * 512);
      gl_lds16(Wkt + (size_t)(n0 + 64 + lrow) * D_ + kc, Bk[p ^ 1] + 2048 + wid * 512);
    }
    short8 af[2], bfq[4], bfk[4];
    const int fo = ((l4 ^ ((l15 >> 1) & 3)) * 8);  // de-swizzle on read
    for (int rt = 0; rt < 2; ++rt)
      af[rt] = *(const short8*)(As[p] + (wm + rt * 16 + l15) * 32 + fo);
    for (int ct = 0; ct < 4; ++ct) {
      bfq[ct] = *(const short8*)(Bq[p] + (wn + ct * 16 + l15) * 32 + fo);
      bfk[ct] = *(const short8*)(Bk[p] + (wn + ct * 16 + l15) * 32 + fo);
    }
    for (int rt = 0; rt < 2; ++rt)
      for (int ct = 0; ct < 4; ++ct) {
        accq[rt][ct] = mfma32(af[rt], bfq[ct], accq[rt][ct]);
        acck[rt][ct] = mfma32(af[rt], bfk[ct], acck[rt][ct]);
      }
    p ^= 1;
  }
  float bvq[4], bvk[4];
  for (int ct = 0; ct < 4; ++ct) {
    bvq[ct] = bq[n0 + wn + ct * 16 + l15];
    bvk[ct] = bk[n0 + wn + ct * 16 + l15];
  }
  for (int rt = 0; rt < 2; ++rt)
    for (int ct = 0; ct < 4; ++ct) {
      const int col = n0 + wn + ct * 16 + l15;
      const int h = col >> 6, d = col & 63;
      const int rowb = m0 + wm + rt * 16 + l4 * 4;
      short4v vv;
      for (int r = 0; r < 4; ++r) {
        const int row = rowb + r;
        const float qv = accq[rt][ct][r] + bvq[ct];
        const float kv = acck[rt][ct][r] + bvk[ct];
        const float sp = fmaxf(kv, 0.f) + __logf(1.f + __expf(-fabsf(kv)));
        q_out[(size_t)row * D_ + col] = __float2bfloat16(qv);
        kt_out[(size_t)row * D_ + col] = __float2bfloat16(sp);
        vv[r] = f2bs(qv + kv);
      }
      const int b = rowb >> 11, s = rowb & 2047;
      // key swizzle p(k) within 64-chunk; s%4==0 -> 4 consecutive stay together
      const int sw = (s & ~63) | (((s >> 4) & 3) << 2) | (((s >> 2) & 3) << 4);
      *(short4v*)(vT + ((size_t)(b * H_ + h) * HD_ + d) * S_ + sw) = vv;
    }
}

// ------- Stage D: flash attention — r27 GLOBAL-DIRECT + REGISTER DBUF.
// (resubmitted unchanged after r12 infra failure — untested hypothesis)
// Evidence chain: r20/r23 calibrated model -> main loop ~80% LDS-pipe-bound.
// r22 (PASSED numerically) proved K and V fragments are directly global-
// addressable but exposed raw latency (no prefetch) -> 128us. r27 keeps
// r22's proven address math and adds latency hiding: K(c+1) register
// ping-pong, V(c) JIT covered by QK+exp. NO LDS, NO barriers in main loop;
// K/V L2-resident (XCD-pinned heads). PV = 2x mfma32 (r23 bijection).
// Epilogue = r22's (1 barrier). Wave = 32 q-rows x full 64-key chunk.
__global__ __launch_bounds__(256, 2) void attn(
    const __hip_bfloat16* __restrict__ qb, const __hip_bfloat16* __restrict__ ktb,
    const __hip_bfloat16* __restrict__ vT, const int* __restrict__ mask,
    float* __restrict__ out) {
  __shared__ float mbuf[128 * 68 + 128];  // epilogue transpose + l[128]; 35328 B
  const int id = blockIdx.x;
  const int xcd = id & 7;
  const int rest = id >> 3;              // 0..63
  const int qt = rest & 15;
  const int hb = (rest >> 4) * 8 + xcd;  // 0..31; same-head q-tiles share XCD
  const int h = hb >> 1, b = hb & 1;
  const int q0 = qt * 128;
  const int tid = threadIdx.x, wid = tid >> 6, lane = tid & 63;
  const int l15 = lane & 15, l4 = lane >> 4;
  const int qs = wid * 32;               // wave's 32 q-rows (2 tiles)
  const __hip_bfloat16* qh = qb + (size_t)b * S_ * D_ + h * HD_;
  const __hip_bfloat16* kh = ktb + (size_t)b * S_ * D_ + h * HD_;
  const __hip_bfloat16* vh = vT + (size_t)(b * H_ + h) * HD_ * S_;

  // Q B-fragments for the wave's 2 q-tiles; mask*scale*log2e folded in
  const float SC = 0.125f * 1.44269504f;
  short8 bq0[2], bq1[2];
#pragma unroll
  for (int T = 0; T < 2; ++T) {
    const int qr = q0 + qs + T * 16 + l15;
    const float mq = (mask[b * S_ + qr] != 0) ? SC : 0.f;
    const short8 r0 = *(const short8*)(qh + (size_t)qr * D_ + l4 * 8);
    const short8 r1 = *(const short8*)(qh + (size_t)qr * D_ + 32 + l4 * 8);
#pragma unroll
    for (int j = 0; j < 8; ++j) {
      bq0[T][j] = f2bs(bs2f(r0[j]) * mq);
      bq1[T][j] = f2bs(bs2f(r1[j]) * mq);
    }
  }

  const float4v zz = {0.f, 0.f, 0.f, 0.f};
  float4v oacc[2][4];  // [T][dt]
#pragma unroll
  for (int T = 0; T < 2; ++T)
#pragma unroll
    for (int dt = 0; dt < 4; ++dt) oacc[T][dt] = zz;
  float4v ls[2] = {zz, zz};

  // per-lane base addresses (r22 proven)
  const __hip_bfloat16* kbase = kh + (size_t)l15 * D_ + l4 * 8;
  const __hip_bfloat16* vbase = vh + (size_t)l15 * S_ + l4 * 16;

  // K register ping-pong; prologue: load K(0) into A
  short8 kA0[4], kA1[4], kB0[4], kB1[4];
#pragma unroll
  for (int t = 0; t < 4; ++t) {
    const __hip_bfloat16* kp = kbase + (size_t)(t * 16) * D_;
    kA0[t] = *(const short8*)kp;
    kA1[t] = *(const short8*)(kp + 32);
  }

#define CHUNK(c, CK0, CK1, NK0, NK1)                                           \
  {                                                                            \
    const int k0_ = (c) * 64;                                                  \
    /* V JIT loads for this chunk (covered by QK+exp below) */                 \
    short8 cv0[4], cv1[4];                                                     \
    _Pragma("unroll")                                                          \
    for (int dt = 0; dt < 4; ++dt) {                                           \
      const __hip_bfloat16* vp = vbase + (size_t)(dt * 16) * S_ + k0_;         \
      cv0[dt] = *(const short8*)vp;                                            \
      cv1[dt] = *(const short8*)(vp + 8);                                      \
    }                                                                          \
    /* K prefetch for next chunk (lands during PV + next QK) */                \
    const int kn_ = ((c) < 31) ? ((c) + 1) * 64 : 0;                           \
    _Pragma("unroll")                                                          \
    for (int t = 0; t < 4; ++t) {                                              \
      const __hip_bfloat16* kp = kbase + (size_t)(kn_ + t * 16) * D_;          \
      NK0[t] = *(const short8*)kp;                                             \
      NK1[t] = *(const short8*)(kp + 32);                                      \
    }                                                                          \
    /* QK -> exp2-domain P */                                                  \
    short8 p01[2], p23[2];                                                     \
    _Pragma("unroll")                                                          \
    for (int T = 0; T < 2; ++T) {                                              \
      float e[4][4];                                                           \
      _Pragma("unroll")                                                        \
      for (int t = 0; t < 4; ++t) {                                            \
        float4v ccv = mfma32(CK0[t], bq0[T], zz);                              \
        ccv = mfma32(CK1[t], bq1[T], ccv);                                     \
        _Pragma("unroll")                                                      \
        for (int r = 0; r < 4; ++r) {                                          \
          e[t][r] = __builtin_amdgcn_exp2f(ccv[r]);                            \
          ls[T][r] += e[t][r];                                                 \
        }                                                                      \
      }                                                                        \
      p01[T] = pk8(e[0], e[1]);                                                \
      p23[T] = pk8(e[2], e[3]);                                                \
    }                                                                          \
    /* PV: 2x mfma32 per (T,dt) via V-block/P k-slot bijection */              \
    _Pragma("unroll")                                                          \
    for (int dt = 0; dt < 4; ++dt)                                             \
      _Pragma("unroll")                                                        \
      for (int T = 0; T < 2; ++T) {                                            \
        oacc[T][dt] = mfma32(cv0[dt], p01[T], oacc[T][dt]);                    \
        oacc[T][dt] = mfma32(cv1[dt], p23[T], oacc[T][dt]);                    \
      }                                                                        \
  }

  for (int cc = 0; cc < 16; ++cc) {
    CHUNK(2 * cc, kA0, kA1, kB0, kB1);
    CHUNK(2 * cc + 1, kB0, kB1, kA0, kA1);
  }
#undef CHUNK

  // ---- epilogue: reduce l; LDS transpose; normalized direct store ----
  float lT[2];
#pragma unroll
  for (int T = 0; T < 2; ++T) {
    lT[T] = (ls[T][0] + ls[T][1]) + (ls[T][2] + ls[T][3]);
    lT[T] += __shfl_xor(lT[T], 16);
    lT[T] += __shfl_xor(lT[T], 32);
  }
  float* ml = mbuf + 128 * 68;
#pragma unroll
  for (int T = 0; T < 2; ++T) {
    const int row = qs + T * 16 + l15;
#pragma unroll
    for (int dt = 0; dt < 4; ++dt)
      *(float4v*)&mbuf[row * 68 + dt * 16 + l4 * 4] = oacc[T][dt];
    if (l4 == 0) ml[row] = lT[T];
  }
  __syncthreads();
  const int qq = tid & 127;              // 64 consecutive lanes -> 64 rows
  const int dg = (tid >> 7) * 32;
  const float li = 1.f / ml[qq];
  float* orow = out + (size_t)(b * S_ + q0 + qq) * D_ + h * HD_ + dg;
#pragma unroll
  for (int i = 0; i < 8; ++i) {
    float4v v = *(const float4v*)&mbuf[qq * 68 + dg + i * 4];
#pragma unroll
    for (int r = 0; r < 4; ++r) v[r] *= li;
    *(float4v*)(orow + i * 4) = v;
  }
}

extern "C" void kernel_launch(void* const* d_in, const int* in_sizes, int n_in,
                              void* d_out, int out_size, void* d_ws, size_t ws_size,
                              hipStream_t stream) {
  const float* hs = (const float*)d_in[0];
  const int* mask = (const int*)d_in[1];
  const float* Wq = (const float*)d_in[2];
  const float* bq = (const float*)d_in[3];
  const float* Wk = (const float*)d_in[4];
  const float* bk = (const float*)d_in[5];
  float* out = (float*)d_out;
  char* ws = (char*)d_ws;
  const size_t MB = 1u << 20;
  __hip_bfloat16* q_b = (__hip_bfloat16*)(ws + 0 * MB);   // [B,S,D] bf16, 8MB
  __hip_bfloat16* k_b = (__hip_bfloat16*)(ws + 8 * MB);   // softplus(k), 8MB
  __hip_bfloat16* vT  = (__hip_bfloat16*)(ws + 16 * MB);  // [B,H,HD,S] key-swizzled, 8MB
  __hip_bfloat16* Wqt = (__hip_bfloat16*)(ws + 24 * MB);  // 2MB
  __hip_bfloat16* Wkt = (__hip_bfloat16*)(ws + 26 * MB);  // 2MB
  __hip_bfloat16* hsb = (__hip_bfloat16*)(ws + 28 * MB);  // [B,S,D] bf16, 8MB

  prep<<<dim3(512), 256, 0, stream>>>(hs, hsb, Wq, Wk, Wqt, Wkt);
  gemm_fused<<<dim3(512), 256, 0, stream>>>(hsb, Wqt, Wkt, bq, bk, q_b, k_b, vT);
  attn<<<dim3(512), 256, 0, stream>>>(q_b, k_b, vT, mask, out);
}

// Round 14
// 149.816 us; speedup vs baseline: 1.5556x; 1.5556x over previous
//
#include <hip/hip_runtime.h>
#include <hip/hip_bf16.h>

#define B_ 2
#define S_ 2048
#define D_ 1024
#define H_ 16
#define HD_ 64

typedef __attribute__((ext_vector_type(8))) short short8;
typedef __attribute__((ext_vector_type(4))) short short4v;
typedef __attribute__((ext_vector_type(4))) float float4v;

typedef const __attribute__((address_space(1))) void* gas_ptr;
typedef __attribute__((address_space(3))) void* las_ptr;

static __device__ inline void gl_lds16(const void* g, void* l) {
  __builtin_amdgcn_global_load_lds((gas_ptr)g, (las_ptr)l, 16, 0, 0);
}

static __device__ inline short f2bs(float x) {
  __hip_bfloat16 h = __float2bfloat16(x);
  union { __hip_bfloat16 h; short s; } u; u.h = h; return u.s;
}
static __device__ inline float bs2f(short s) {
  union { short s; __hip_bfloat16 h; } u; u.s = s; return __bfloat162float(u.h);
}
// packed f32x8 -> bf16x8 (v_cvt_pk_bf16_f32 x4); a = key-tile lo, b = key-tile hi
static __device__ inline short8 pk8(const float* a, const float* b) {
  union { __hip_bfloat162 h[4]; short8 s; } u;
  u.h[0] = __float22bfloat162_rn(float2{a[0], a[1]});
  u.h[1] = __float22bfloat162_rn(float2{a[2], a[3]});
  u.h[2] = __float22bfloat162_rn(float2{b[0], b[1]});
  u.h[3] = __float22bfloat162_rn(float2{b[2], b[3]});
  return u.s;
}

static __device__ inline float4v mfma32(short8 a, short8 b, float4v c) {
  return __builtin_amdgcn_mfma_f32_16x16x32_bf16(a, b, c, 0, 0, 0);
}

// ------- Stage A: prep (r26): 512 blocks; 4 hs-cvt jobs + 1 W-transpose job.
__global__ __launch_bounds__(256) void prep(
    const float* __restrict__ hs, __hip_bfloat16* __restrict__ hsb,
    const float* __restrict__ Wq, const float* __restrict__ Wk,
    __hip_bfloat16* __restrict__ Wqt, __hip_bfloat16* __restrict__ Wkt) {
  __shared__ float t[64][65];
  const int id = blockIdx.x;
#pragma unroll
  for (int j = 0; j < 4; ++j) {
    const size_t i = (((size_t)id * 4 + j) * 256 + threadIdx.x) * 8;
    const float4v a0 = ((const float4v*)(hs + i))[0];
    const float4v a1 = ((const float4v*)(hs + i))[1];
    short8 s;
#pragma unroll
    for (int jj = 0; jj < 4; ++jj) { s[jj] = f2bs(a0[jj]); s[4 + jj] = f2bs(a1[jj]); }
    *(short8*)(hsb + i) = s;
  }
  const float* W = (id >> 8) ? Wk : Wq;
  __hip_bfloat16* Wt = (id >> 8) ? Wkt : Wqt;
  const int n0 = (id & 15) * 64, k0 = ((id >> 4) & 15) * 64;
  const int c = threadIdx.x & 63, r0 = threadIdx.x >> 6;
  for (int i = 0; i < 16; ++i) {
    const int r = i * 4 + r0;
    t[c][r] = W[(size_t)(k0 + r) * D_ + n0 + c];
  }
  __syncthreads();
  for (int i = 0; i < 16; ++i) {
    const int rr = i * 4 + r0;
    Wt[(size_t)(n0 + rr) * D_ + k0 + c] = __float2bfloat16(t[rr][c]);
  }
}

// ---- Stage B (fused GEMM+prep): r26 K-loop (XCD owns one W-panel, xcd=nt).
// r28 COALESCED EPILOGUE: r25 profile showed WRITE_SIZE 33MB vs 24MB output
// (~10MB write amplification). Old stores: vT = per-lane 8B scatter at 4KB
// lane stride (1 fragment per 64B line); q/kt = 64 scalar 2B stores. New:
// after the K-loop (+1 barrier), stage q/kt as LDS [64][136] and v as LDS
// [128][72] (sw group-permutation applied on the LDS write), then copy out
// as fully-coalesced short8 rows (256B segments for q/kt, 128B for vT).
// K-loop / staging / MFMA untouched. LDS grows 40->53.2KB (2 blocks/CU ok).
__global__ __launch_bounds__(256, 2) void gemm_fused(
    const __hip_bfloat16* __restrict__ hsb,
    const __hip_bfloat16* __restrict__ Wqt, const __hip_bfloat16* __restrict__ Wkt,
    const float* __restrict__ bq, const float* __restrict__ bk,
    __hip_bfloat16* __restrict__ q_out, __hip_bfloat16* __restrict__ kt_out,
    __hip_bfloat16* __restrict__ vT) {
  const int id = blockIdx.x;
  const int nt = id & 7;                           // n-block 0..7 == XCD
  const int mt = id >> 3;                          // m-tile 0..63
  const int n0 = nt * 128, m0 = mt * 64;
  // unified LDS: K-loop carve = 20480 shorts (40KB); epilogue carve = 26624
  __shared__ short gsm[27648];                     // 54KB
  __hip_bfloat16* As = (__hip_bfloat16*)gsm;              // [2][64*32]
  __hip_bfloat16* Bq = (__hip_bfloat16*)(gsm + 4096);     // [2][128*32]
  __hip_bfloat16* Bk = (__hip_bfloat16*)(gsm + 12288);    // [2][128*32]
  const int tid = threadIdx.x, wid = tid >> 6, lane = tid & 63;
  const int wm = (wid >> 1) * 32, wn = (wid & 1) * 64;
  const int l15 = lane & 15, l4 = lane >> 4;
  const float4v zz = {0.f, 0.f, 0.f, 0.f};
  float4v accq[2][4], acck[2][4];
  for (int i = 0; i < 2; ++i)
    for (int j = 0; j < 4; ++j) { accq[i][j] = zz; acck[i][j] = zz; }
  const int lrow = wid * 16 + (lane >> 2);
  const int lk8 = (((lane & 3) ^ ((lane >> 3) & 3)) * 8);
  {
    gl_lds16(hsb + (size_t)(m0 + lrow) * D_ + lk8, As + wid * 512);
    gl_lds16(Wqt + (size_t)(n0 + lrow) * D_ + lk8, Bq + wid * 512);
    gl_lds16(Wqt + (size_t)(n0 + 64 + lrow) * D_ + lk8, Bq + 2048 + wid * 512);
    gl_lds16(Wkt + (size_t)(n0 + lrow) * D_ + lk8, Bk + wid * 512);
    gl_lds16(Wkt + (size_t)(n0 + 64 + lrow) * D_ + lk8, Bk + 2048 + wid * 512);
  }
  int p = 0;
  for (int kb = 0; kb < 32; ++kb) {
    __syncthreads();  // buf[p] staged (vm drained); prev frag reads done
    if (kb < 31) {
      const int kc = (kb + 1) * 32 + lk8;
      gl_lds16(hsb + (size_t)(m0 + lrow) * D_ + kc, As + (p ^ 1) * 2048 + wid * 512);
      gl_lds16(Wqt + (size_t)(n0 + lrow) * D_ + kc, Bq + (p ^ 1) * 4096 + wid * 512);
      gl_lds16(Wqt + (size_t)(n0 + 64 + lrow) * D_ + kc, Bq + (p ^ 1) * 4096 + 2048 + wid * 512);
      gl_lds16(Wkt + (size_t)(n0 + lrow) * D_ + kc, Bk + (p ^ 1) * 4096 + wid * 512);
      gl_lds16(Wkt + (size_t)(n0 + 64 + lrow) * D_ + kc, Bk + (p ^ 1) * 4096 + 2048 + wid * 512);
    }
    short8 af[2], bfq[4], bfk[4];
    const int fo = ((l4 ^ ((l15 >> 1) & 3)) * 8);  // de-swizzle on read
    for (int rt = 0; rt < 2; ++rt)
      af[rt] = *(const short8*)(As + p * 2048 + (wm + rt * 16 + l15) * 32 + fo);
    for (int ct = 0; ct < 4; ++ct) {
      bfq[ct] = *(const short8*)(Bq + p * 4096 + (wn + ct * 16 + l15) * 32 + fo);
      bfk[ct] = *(const short8*)(Bk + p * 4096 + (wn + ct * 16 + l15) * 32 + fo);
    }
    for (int rt = 0; rt < 2; ++rt)
      for (int ct = 0; ct < 4; ++ct) {
        accq[rt][ct] = mfma32(af[rt], bfq[ct], accq[rt][ct]);
        acck[rt][ct] = mfma32(af[rt], bfk[ct], acck[rt][ct]);
      }
    p ^= 1;
  }
  // ---- r28 epilogue: LDS-staged, coalesced copyout ----
  __syncthreads();  // all frag reads done; LDS reused for output tiles
  short* eq = gsm;                  // [64][136]  q bf16
  short* ek = gsm + 64 * 136;       // [64][136]  softplus(k) bf16
  short* ev = gsm + 2 * 64 * 136;   // [128][72]  v = q+k bf16, sw-permuted
  float bvq[4], bvk[4];
  for (int ct = 0; ct < 4; ++ct) {
    bvq[ct] = bq[n0 + wn + ct * 16 + l15];
    bvk[ct] = bk[n0 + wn + ct * 16 + l15];
  }
  for (int rt = 0; rt < 2; ++rt) {
    const int rl = wm + rt * 16 + l4 * 4;  // local row base 0..63
    // group-of-4 key permutation within the 64-chunk (sw low bits)
    const int swl = (((rl >> 4) & 3) << 2) | (((rl >> 2) & 3) << 4);
    for (int ct = 0; ct < 4; ++ct) {
      const int cl = wn + ct * 16 + l15;   // local col 0..127
      short4v vv;
      for (int r = 0; r < 4; ++r) {
        const float qv = accq[rt][ct][r] + bvq[ct];
        const float kv = acck[rt][ct][r] + bvk[ct];
        const float sp = fmaxf(kv, 0.f) + __logf(1.f + __expf(-fabsf(kv)));
        eq[(rl + r) * 136 + cl] = f2bs(qv);
        ek[(rl + r) * 136 + cl] = f2bs(sp);
        vv[r] = f2bs(qv + kv);
      }
      *(short4v*)(ev + cl * 72 + swl) = vv;
    }
  }
  __syncthreads();
  // q/kt: 64 rows x 128 cols bf16 -> 256B contiguous per row
  const int bb = m0 >> 11, sbase = m0 & 2047;
#pragma unroll
  for (int i = 0; i < 4; ++i) {
    const int e = i * 256 + tid;           // 0..1023
    const int row = e >> 4, c8 = (e & 15) * 8;
    const size_t g = (size_t)(m0 + row) * D_ + n0 + c8;
    *(short8*)(q_out + g) = *(const short8*)(eq + row * 136 + c8);
    *(short8*)(kt_out + g) = *(const short8*)(ek + row * 136 + c8);
  }
  // vT: 128 rows (h,d) x 64 key-slots bf16 -> 128B contiguous per row
#pragma unroll
  for (int i = 0; i < 4; ++i) {
    const int e = i * 256 + tid;           // 0..1023
    const int vrow = e >> 3, s8 = (e & 7) * 8;
    const int col = n0 + vrow;
    const int h = col >> 6, d = col & 63;
    *(short8*)(vT + ((size_t)(bb * H_ + h) * HD_ + d) * S_ + sbase + s8) =
        *(const short8*)(ev + vrow * 72 + s8);
  }
}

// ------- Stage D: flash attention — r23 structure, byte-identical (48.3us,
// best known; declared structurally done after r20/r21/r22/r27 falsified
// traffic/occupancy/barrier-free/reg-prefetch levers). Key-split waves,
// 128-key chunks, PV as 2x mfma32 via the V-block/P k-slot bijection. -------
__global__ __launch_bounds__(256, 2) void attn(
    const __hip_bfloat16* __restrict__ qb, const __hip_bfloat16* __restrict__ ktb,
    const __hip_bfloat16* __restrict__ vT, const int* __restrict__ mask,
    float* __restrict__ out) {
  // buffer: kt0[4096] kt1[4096] v0[4096] v1[4096] shorts; 2 bufs = 65536 B
  __shared__ short smem[32768];
  const int id = blockIdx.x;
  const int xcd = id & 7;
  const int rest = id >> 3;              // 0..63
  const int q0 = (rest & 15) * 128;      // q-tile
  const int hb = (rest >> 4) * 8 + xcd;  // 0..31
  const int h = hb >> 1, b = hb & 1;
  const int tid = threadIdx.x, wid = tid >> 6, lane = tid & 63;
  const int l15 = lane & 15, l4 = lane >> 4;
  const int qs = (wid & 1) * 64;         // q-segment (4 tiles of 16)
  const int kh = wid >> 1;               // key-half (64 keys of the 128-chunk)
  const __hip_bfloat16* qh = qb + (size_t)b * S_ * D_ + h * HD_;
  const __hip_bfloat16* kh_ = ktb + (size_t)b * S_ * D_ + h * HD_;
  const __hip_bfloat16* vh = vT + (size_t)(b * H_ + h) * HD_ * S_;
  // staging map (cooperative, tid-based, both halves): row=tid>>2, blocks b0,b0+4
  const int srow = tid >> 2;
  const int b0 = tid & 3;
  const int ssw = ((srow & 1) << 2) | ((srow >> 1) & 3);  // s(row)
  const int w0 = srow * 64 + ((b0 ^ ssw) * 8);
  const int w1 = srow * 64 + (((b0 + 4) ^ ssw) * 8);

  // Q B-fragments for the wave's 4 q-tiles; mask*scale*log2e folded in
  const float SC = 0.125f * 1.44269504f;
  short8 bq0[4], bq1[4];
#pragma unroll
  for (int T = 0; T < 4; ++T) {
    const int qr = q0 + qs + T * 16 + l15;
    const float mq = (mask[b * S_ + qr] != 0) ? SC : 0.f;
    const short8 r0 = *(const short8*)(qh + (size_t)qr * D_ + l4 * 8);
    const short8 r1 = *(const short8*)(qh + (size_t)qr * D_ + 32 + l4 * 8);
#pragma unroll
    for (int j = 0; j < 8; ++j) {
      bq0[T][j] = f2bs(bs2f(r0[j]) * mq);
      bq1[T][j] = f2bs(bs2f(r1[j]) * mq);
    }
  }

  // fragment read offsets (s(row)-swizzled; row&7 == l15&7 for all reads)
  const int lsw = ((l15 & 1) << 2) | ((l15 >> 1) & 3);
  const int ak0off = l15 * 64 + ((l4 ^ lsw) * 8);          // + t*1024
  const int ak1off = l15 * 64 + (((l4 + 4) ^ lsw) * 8);
  const int vb0off = ((2 * l4) ^ lsw) * 8;                 // + row*64
  const int vb1off = ((2 * l4 + 1) ^ lsw) * 8;

  const float4v zz = {0.f, 0.f, 0.f, 0.f};
  float4v oacc[4][4];  // [T][dt]
#pragma unroll
  for (int T = 0; T < 4; ++T)
#pragma unroll
    for (int dt = 0; dt < 4; ++dt) oacc[T][dt] = zz;
  float4v ls[4] = {zz, zz, zz, zz};  // per-T, per-r partial sums

  // prefetch chunk 0 (two 64-key subchunks, cooperative)
  short8 gk0[2], gk1[2], gv0[2], gv1[2];
#pragma unroll
  for (int u = 0; u < 2; ++u) {
    gk0[u] = *(const short8*)(kh_ + (size_t)(u * 64 + srow) * D_ + b0 * 8);
    gk1[u] = *(const short8*)(kh_ + (size_t)(u * 64 + srow) * D_ + b0 * 8 + 32);
    gv0[u] = *(const short8*)(vh + (size_t)srow * S_ + u * 64 + b0 * 8);
    gv1[u] = *(const short8*)(vh + (size_t)srow * S_ + u * 64 + b0 * 8 + 32);
  }

  int pb = 0;
  for (int c = 0; c < 16; ++c) {
    short* bufp = smem + pb * 16384;
#pragma unroll
    for (int u = 0; u < 2; ++u) {
      *(short8*)(bufp + u * 4096 + w0) = gk0[u];
      *(short8*)(bufp + u * 4096 + w1) = gk1[u];
      *(short8*)(bufp + 8192 + u * 4096 + w0) = gv0[u];
      *(short8*)(bufp + 8192 + u * 4096 + w1) = gv1[u];
    }
    __syncthreads();
    if (c < 15) {
      const int kb = (c + 1) * 128;
#pragma unroll
      for (int u = 0; u < 2; ++u) {
        gk0[u] = *(const short8*)(kh_ + (size_t)(kb + u * 64 + srow) * D_ + b0 * 8);
        gk1[u] = *(const short8*)(kh_ + (size_t)(kb + u * 64 + srow) * D_ + b0 * 8 + 32);
        gv0[u] = *(const short8*)(vh + (size_t)srow * S_ + kb + u * 64 + b0 * 8);
        gv1[u] = *(const short8*)(vh + (size_t)srow * S_ + kb + u * 64 + b0 * 8 + 32);
      }
    }
    const short* kbase = bufp + kh * 4096;           // this wave's key-half
    const short* vbase = bufp + 8192 + kh * 4096;
    // ---- phase 1: QK -> exp2-domain P, packed per (lo,hi) tile pair ----
    short8 ak0[4], ak1[4];
#pragma unroll
    for (int t = 0; t < 4; ++t) {
      ak0[t] = *(const short8*)(kbase + t * 1024 + ak0off);
      ak1[t] = *(const short8*)(kbase + t * 1024 + ak1off);
    }
    short8 p01[4], p23[4];  // [T]
#pragma unroll
    for (int T = 0; T < 4; ++T) {
      float e[4][4];
#pragma unroll
      for (int t = 0; t < 4; ++t) {
        float4v cc = zz;
        cc = mfma32(ak0[t], bq0[T], cc);
        cc = mfma32(ak1[t], bq1[T], cc);
#pragma unroll
        for (int r = 0; r < 4; ++r) {
          e[t][r] = __builtin_amdgcn_exp2f(cc[r]); ls[T][r] += e[t][r];
        }
      }
      p01[T] = pk8(e[0], e[1]);
      p23[T] = pk8(e[2], e[3]);
    }
    // ---- phase 2: PV, 2x mfma32 per (T,dt) (V-block/P k-slot bijection) ----
#pragma unroll
    for (int dt = 0; dt < 4; ++dt) {
      const int rb = (dt * 16 + l15) * 64;
      const short8 av0 = *(const short8*)(vbase + rb + vb0off);
      const short8 av1 = *(const short8*)(vbase + rb + vb1off);
#pragma unroll
      for (int T = 0; T < 4; ++T) {
        oacc[T][dt] = mfma32(av0, p01[T], oacc[T][dt]);
        oacc[T][dt] = mfma32(av1, p23[T], oacc[T][dt]);
      }
    }
    pb ^= 1;
  }
  // ---- epilogue: reduce l per tile; combine key-halves; normalize ----
  float lT[4];
#pragma unroll
  for (int T = 0; T < 4; ++T) {
    lT[T] = (ls[T][0] + ls[T][1]) + (ls[T][2] + ls[T][3]);
    lT[T] += __shfl_xor(lT[T], 16);
    lT[T] += __shfl_xor(lT[T], 32);
  }
  __syncthreads();
  float* mbuf = (float*)smem;            // [128][68]
  float* mlb = (float*)smem + 128 * 68;  // [128]
  if (kh == 0) {
#pragma unroll
    for (int T = 0; T < 4; ++T) {
      const int row = qs + T * 16 + l15;
#pragma unroll
      for (int dt = 0; dt < 4; ++dt)
        *(float4v*)&mbuf[row * 68 + dt * 16 + l4 * 4] = oacc[T][dt];
      if (l4 == 0) mlb[row] = lT[T];
    }
  }
  __syncthreads();
  if (kh == 1) {
#pragma unroll
    for (int T = 0; T < 4; ++T) {
      const int row = qs + T * 16 + l15;
#pragma unroll
      for (int dt = 0; dt < 4; ++dt) {
        float4v v = *(const float4v*)&mbuf[row * 68 + dt * 16 + l4 * 4];
        v += oacc[T][dt];
        *(float4v*)&mbuf[row * 68 + dt * 16 + l4 * 4] = v;
      }
      if (l4 == 0) mlb[row] += lT[T];
    }
  }
  __syncthreads();
  const int qq = tid & 127;              // 64 consecutive lanes -> 64 rows
  const int dg = (tid >> 7) * 32;
  const float li = 1.f / mlb[qq];
  float* orow = out + (size_t)(b * S_ + q0 + qq) * D_ + h * HD_ + dg;
#pragma unroll
  for (int i = 0; i < 8; ++i) {
    float4v v = *(const float4v*)&mbuf[qq * 68 + dg + i * 4];
#pragma unroll
    for (int r = 0; r < 4; ++r) v[r] *= li;
    *(float4v*)(orow + i * 4) = v;
  }
}

extern "C" void kernel_launch(void* const* d_in, const int* in_sizes, int n_in,
                              void* d_out, int out_size, void* d_ws, size_t ws_size,
                              hipStream_t stream) {
  const float* hs = (const float*)d_in[0];
  const int* mask = (const int*)d_in[1];
  const float* Wq = (const float*)d_in[2];
  const float* bq = (const float*)d_in[3];
  const float* Wk = (const float*)d_in[4];
  const float* bk = (const float*)d_in[5];
  float* out = (float*)d_out;
  char* ws = (char*)d_ws;
  const size_t MB = 1u << 20;
  __hip_bfloat16* q_b = (__hip_bfloat16*)(ws + 0 * MB);   // [B,S,D] bf16, 8MB
  __hip_bfloat16* k_b = (__hip_bfloat16*)(ws + 8 * MB);   // softplus(k), 8MB
  __hip_bfloat16* vT  = (__hip_bfloat16*)(ws + 16 * MB);  // [B,H,HD,S] key-swizzled, 8MB
  __hip_bfloat16* Wqt = (__hip_bfloat16*)(ws + 24 * MB);  // 2MB
  __hip_bfloat16* Wkt = (__hip_bfloat16*)(ws + 26 * MB);  // 2MB
  __hip_bfloat16* hsb = (__hip_bfloat16*)(ws + 28 * MB);  // [B,S,D] bf16, 8MB

  prep<<<dim3(512), 256, 0, stream>>>(hs, hsb, Wq, Wk, Wqt, Wkt);
  gemm_fused<<<dim3(512), 256, 0, stream>>>(hsb, Wqt, Wkt, bq, bk, q_b, k_b, vT);
  attn<<<dim3(512), 256, 0, stream>>>(q_b, k_b, vT, mask, out);
}